// Round 14
// baseline (4555.173 us; speedup 1.0000x reference)
//
#include <hip/hip_runtime.h>

using bf16x8 = __attribute__((ext_vector_type(8))) short;
using f32x4  = __attribute__((ext_vector_type(4))) float;

#define HW   4096
#define CIN  256
#define OFFC 166

// ws layout: [0, WBYTES) bf16 weights fragment-major; then quad feat pack.
#define WS3_BASE 0
#define WS5_BASE 589824
#define WS7_BASE 2228224
#define WS_TOTAL 5439488                 // ushorts
#define WBYTES   (WS_TOTAL * 2)
#define QELEMS   1048576                 // 2 b * 128 c2 * 4096 pos
#define QBYTES   (QELEMS * 16)           // 16 MB quad pack

__device__ __forceinline__ unsigned short f2bf(float f) {
    unsigned u = __builtin_bit_cast(unsigned, f);
    return (unsigned short)((u + 0x7fffu + ((u >> 16) & 1u)) >> 16);   // RNE
}
__device__ __forceinline__ float bf2f(unsigned v) {
    return __builtin_bit_cast(float, v << 16);
}
__device__ __forceinline__ unsigned cvt_pk_bf16(float lo, float hi) {
    unsigned r;
    asm volatile("v_cvt_pk_bf16_f32 %0, %1, %2" : "=v"(r) : "v"(lo), "v"(hi));
    return r;
}

// ---------------- weight prep: fp32 [o][c][kh][kw] -> bf16 fragment-major ----------------
// ws[((ks*16+gm)*64+l)*8+e] = w[o=gm*16+(l&15)][c][j], r=ks*32+(l>>4)*8+e, j=r>>8, c=r&255
// (16x16x32 A-frag layout — byte-identical to the passing kernels)
__global__ __launch_bounds__(256)
void mcdc_prep_w(const float* __restrict__ w3, const float* __restrict__ w5,
                 const float* __restrict__ w7, unsigned short* __restrict__ ws)
{
    int idx = blockIdx.x * 256 + threadIdx.x;
    const float* src; int KKv, base;
    if (idx < WS5_BASE)      { src = w3; KKv = 9;  base = WS3_BASE; }
    else if (idx < WS7_BASE) { src = w5; KKv = 25; base = WS5_BASE; }
    else                     { src = w7; KKv = 49; base = WS7_BASE; }
    int rel = idx - base;
    int e  = rel & 7;
    int l  = (rel >> 3) & 63;
    int gm = (rel >> 9) & 15;
    int ks = rel >> 13;
    int o  = gm * 16 + (l & 15);
    int r  = ks * 32 + (l >> 4) * 8 + e;
    ws[idx] = f2bf(src[((size_t)o * CIN + (r & 255)) * KKv + (r >> 8)]);
}

// ---------------- feat prep: corner-quad, 2 c-planes interleaved ----------------
// q[(b*128+c2)*4096 + y*64+x] = { c0:{f(y,x),f(y,xp)},{f(yp,x),f(yp,xp)}, c1: same }
__global__ __launch_bounds__(256)
void mcdc_prep_q(const float* __restrict__ feat, uint4* __restrict__ q)
{
    int idx = blockIdx.x * 256 + threadIdx.x;          // [0, QELEMS)
    int b = idx >> 19, c2 = (idx >> 12) & 127, pos = idx & 4095;
    int y = pos >> 6, x = pos & 63;
    int xp = min(x + 1, 63), yp = min(y + 1, 63);
    const float* f0 = feat + ((size_t)(b * CIN + 2 * c2)) * HW;
    const float* f1 = f0 + HW;
    uint4 o;
    o.x = (unsigned)f2bf(f0[y  * 64 + x]) | ((unsigned)f2bf(f0[y  * 64 + xp]) << 16);
    o.y = (unsigned)f2bf(f0[yp * 64 + x]) | ((unsigned)f2bf(f0[yp * 64 + xp]) << 16);
    o.z = (unsigned)f2bf(f1[y  * 64 + x]) | ((unsigned)f2bf(f1[y  * 64 + xp]) << 16);
    o.w = (unsigned)f2bf(f1[yp * 64 + x]) | ((unsigned)f2bf(f1[yp * 64 + xp]) << 16);
    q[idx] = o;
}

// ---------------- fused sample + GEMM ----------------
// 512 threads = 8 waves. BM=256, BN=64 px, K-range [ks0,ks1).
// Wave: mh=wid&1 (m-half, mf=8), pq=wid>>1 (16-px quarter, nf=1)  [PROVEN mapping — untouched].
// Staging: thread = (pixel pxs=tid&63, c-quad coct=tid>>6); reg meta; 2-deep gather pipe.
// A-tile deduped through LDS via REG-COPY (R12-proven codegen shape; R13's global_load_lds
// variant triggered scratch thrash). awrite = two full-coverage 16B-stride passes ->
// all 32 banks active, conflict-free. sA = linear copy of the 16KB kstep block; read
// offsets IDENTICAL to the proven kernel: (mh*8+mf)*512+lane*8 — MFMA inputs bit-identical.
template<int K, int CH_OFF, int OC_OFF, bool ATOMIC, int MODE>
__device__ __forceinline__ void dconv(
    const float* __restrict__ feat, const float* __restrict__ off,
    const unsigned short* __restrict__ wsA, const uint4* __restrict__ qf,
    float* __restrict__ out, int b, int p0, int ks0, int ks1,
    unsigned short (&sB)[2][64][40], unsigned short (&sA)[2][8192])
{
    const int tid  = threadIdx.x;
    const int lane = tid & 63;
    const int wid  = tid >> 6;
    const int mh   = wid & 1;
    const int pq   = wid >> 1;
    const int pxs  = tid & 63;          // staging pixel
    const int coct = wid;               // staging c-quad (4 c-planes)

    const int pix = p0 + pxs, py = pix >> 6, px = pix & 63;

    // per-thread bilinear meta, double-slotted by j&1
    const uint4* qbase[2];
    const float* fbase[2];
    int   fxo[2], fyo[2];
    float mw[2][4];

    auto computeMeta = [&](int j) {
        const int s = j & 1;
        const float* ob = off + ((size_t)(b * OFFC + CH_OFF + 2 * j)) * HW + pix;
        const float oy = ob[0], ox = ob[HW];
        const float sy = (float)py + oy, sx = (float)px + ox;
        const float fy = floorf(sy), fx = floorf(sx);
        const float dy = sy - fy, dx = sx - fx;
        const int y0 = (int)fy, x0 = (int)fx;
        const bool vy0 = (y0 >= 0) & (y0 < 64), vy1 = (y0 >= -1) & (y0 < 63);
        const bool vx0 = (x0 >= 0) & (x0 < 64), vx1 = (x0 >= -1) & (x0 < 63);
        float w00 = (1.f - dy) * (1.f - dx) * ((vy0 && vx0) ? 1.f : 0.f);
        float w01 = (1.f - dy) * dx         * ((vy0 && vx1) ? 1.f : 0.f);
        float w10 = dy * (1.f - dx)         * ((vy1 && vx0) ? 1.f : 0.f);
        float w11 = dy * dx                 * ((vy1 && vx1) ? 1.f : 0.f);
        const int ya  = min(max(y0, 0), 63),     xa  = min(max(x0, 0), 63);
        const int y1c = min(max(y0 + 1, 0), 63), x1c = min(max(x0 + 1, 0), 63);
        // fold degenerate axes into weights -> stage needs no selects
        if (x1c == xa) { w00 += w01; w10 += w11; w01 = 0.f; w11 = 0.f; }
        if (y1c == ya) { w00 += w10; w01 += w11; w10 = 0.f; w11 = 0.f; }
        mw[s][0] = w00; mw[s][1] = w01; mw[s][2] = w10; mw[s][3] = w11;
        const int base = ya * 64 + xa;
        if (MODE == 0) {
            qbase[s] = qf + (((size_t)(b * 128 + coct * 2)) << 12) + base;
        } else {
            fbase[s] = feat + ((size_t)(b * CIN)) * HW + base;
            fxo[s] = x1c - xa; fyo[s] = (y1c - ya) * 64;
        }
    };

    uint4 gA0, gA1, gB0, gB1;            // MODE0 gather payload
    float fA[16], fB[16];                // MODE2 gather payload (dead under MODE0)
    uint4 aP0, aP1, aQ0, aQ1;            // A-tile payload sets (32B/thread each)

    auto gissue = [&](int ks, uint4& g0, uint4& g1, float* f) {
        const int s = (ks >> 3) & 1;
        if (MODE == 0) {
            const uint4* qp = qbase[s] + ((ks & 7) << 16);
            g0 = qp[0];
            g1 = qp[4096];
        } else {
            const float* fp = fbase[s] + ((size_t)((ks & 7) * 32 + coct * 4)) * HW;
            const int xo = fxo[s], yo = fyo[s];
#pragma unroll
            for (int e = 0; e < 4; ++e) {
                f[e*4+0] = fp[0]; f[e*4+1] = fp[xo]; f[e*4+2] = fp[yo]; f[e*4+3] = fp[yo+xo];
                fp += HW;
            }
        }
    };

    // A-tile payload: thread tid covers uint4 #tid and #(512+tid) of the 16KB kstep block
    auto gissueA = [&](int ks, uint4& h0, uint4& h1) {
        const uint4* src = (const uint4*)(wsA + (size_t)ks * 8192);
        h0 = src[tid];
        h1 = src[512 + tid];
    };
    // two full-coverage passes at 16B lane stride -> all 32 banks, conflict-free
    auto awrite = [&](int ks, const uint4& h0, const uint4& h1) {
        uint4* dst = (uint4*)(&sA[ks & 1][0]);
        dst[tid]       = h0;
        dst[512 + tid] = h1;
    };

    auto bwrite = [&](int ks, const uint4& g0, const uint4& g1, const float* f) {
        const int s = (ks >> 3) & 1;
        const float w00 = mw[s][0], w01 = mw[s][1], w10 = mw[s][2], w11 = mw[s][3];
        float v[4];
        if (MODE == 0) {
            v[0] = w00*bf2f(g0.x & 0xffff) + w01*bf2f(g0.x >> 16)
                 + w10*bf2f(g0.y & 0xffff) + w11*bf2f(g0.y >> 16);
            v[1] = w00*bf2f(g0.z & 0xffff) + w01*bf2f(g0.z >> 16)
                 + w10*bf2f(g0.w & 0xffff) + w11*bf2f(g0.w >> 16);
            v[2] = w00*bf2f(g1.x & 0xffff) + w01*bf2f(g1.x >> 16)
                 + w10*bf2f(g1.y & 0xffff) + w11*bf2f(g1.y >> 16);
            v[3] = w00*bf2f(g1.z & 0xffff) + w01*bf2f(g1.z >> 16)
                 + w10*bf2f(g1.w & 0xffff) + w11*bf2f(g1.w >> 16);
        } else {
#pragma unroll
            for (int e = 0; e < 4; ++e)
                v[e] = w00*f[e*4] + w01*f[e*4+1] + w10*f[e*4+2] + w11*f[e*4+3];
        }
        uint2 wv;
        wv.x = cvt_pk_bf16(v[0], v[1]);
        wv.y = cvt_pk_bf16(v[2], v[3]);
        *(uint2*)(&sB[ks & 1][pxs][coct * 4]) = wv;
    };

    f32x4 acc[8];
#pragma unroll
    for (int i = 0; i < 8; ++i) acc[i] = f32x4{0.f, 0.f, 0.f, 0.f};

    auto iter = [&](int ks, uint4& gc0, uint4& gc1, float* fc,
                    uint4& gn0, uint4& gn1, float* fn,
                    uint4& wc0, uint4& wc1, uint4& wn0, uint4& wn1) {
        __syncthreads();                                  // sB/sA[ks&1] staged by all
        if ((ks & 7) == 6 && ks + 2 < ks1) computeMeta((ks + 2) >> 3);
        { const int kg = min(ks + 2, ks1 - 1); gissue(kg, gn0, gn1, fn); gissueA(kg, wn0, wn1); }
        const bf16x8 bfr = *(const bf16x8*)(&sB[ks & 1][pq * 16 + (lane & 15)][(lane >> 4) * 8]);
        bf16x8 a[8];
#pragma unroll
        for (int mf = 0; mf < 8; ++mf)                    // identical offsets, via LDS
            a[mf] = *(const bf16x8*)(&sA[ks & 1][(mh * 8 + mf) * 512 + lane * 8]);
        if (ks + 1 < ks1) {
            bwrite(ks + 1, gc0, gc1, fc);                 // VALU + LDS writes fill load shadow
            awrite(ks + 1, wc0, wc1);
        }
#pragma unroll
        for (int mf = 0; mf < 8; ++mf)
            acc[mf] = __builtin_amdgcn_mfma_f32_16x16x32_bf16(a[mf], bfr, acc[mf], 0, 0, 0);
    };

    // prologue: meta, payloads for ks0 and ks0+1, stage ks0 (B and A)
    computeMeta(ks0 >> 3);
    gissue(ks0, gA0, gA1, fA);
    gissueA(ks0, aP0, aP1);
    gissue(min(ks0 + 1, ks1 - 1), gB0, gB1, fB);
    gissueA(min(ks0 + 1, ks1 - 1), aQ0, aQ1);
    bwrite(ks0, gA0, gA1, fA);
    awrite(ks0, aP0, aP1);

    for (int ks = ks0; ks < ks1; ks += 2) {               // all splits even-length
        iter(ks,     gB0, gB1, fB, gA0, gA1, fA, aQ0, aQ1, aP0, aP1);
        iter(ks + 1, gA0, gA1, fA, gB0, gB1, fB, aP0, aP1, aQ0, aQ1);
    }

    // epilogue: D layout col=lane&15, row=(lane>>4)*4+r
#pragma unroll
    for (int mf = 0; mf < 8; ++mf) {
#pragma unroll
        for (int r = 0; r < 4; ++r) {
            const int o = OC_OFF + mh * 128 + mf * 16 + (lane >> 4) * 4 + r;
            const int p = p0 + pq * 16 + (lane & 15);
            float* dst = out + ((size_t)(b * 768 + o)) * HW + p;
            if (ATOMIC) atomicAdd(dst, acc[mf][r]);
            else        *dst = acc[mf][r];
        }
    }
}

// 1536 = 8 xcd * 16 tiles * 12 roles. XCD-pinned; role 0 (k3, longest) dispatched first.
template<int MODE>
__global__ __launch_bounds__(512, 6)
void mcdc_main(const float* __restrict__ feat, const float* __restrict__ off,
               const unsigned short* __restrict__ ws, const uint4* __restrict__ qf,
               float* __restrict__ out)
{
    __shared__ __attribute__((aligned(16))) unsigned short sB[2][64][40];
    __shared__ __attribute__((aligned(16))) unsigned short sA[2][8192];

    const int bid  = blockIdx.x;
    const int xcd  = bid & 7;
    const int tl   = (bid >> 3) & 15;
    const int role = bid >> 7;              // 0..11
    const int tile = xcd * 16 + tl;         // 0..127
    const int b    = tile >> 6;
    const int p0   = (tile & 63) << 6;

    if (role == 0) {                        // k=3: 72 ksteps, whole, plain store
        dconv<3, 0, 0, false, MODE>(feat, off, ws + WS3_BASE, qf, out, b, p0, 0, 72, sB, sA);
    } else if (role <= 7) {                 // k=7: 7 splits of 56
        const int r = role - 1;
        dconv<7, 68, 512, true, MODE>(feat, off, ws + WS7_BASE, qf, out, b, p0,
                                      r * 56, r * 56 + 56, sB, sA);
    } else {                                // k=5: 200 = 48+48+48+56
        const int r = role - 8;
        const int ks0 = r * 48;
        const int ks1 = (r == 3) ? 200 : ks0 + 48;
        dconv<5, 18, 256, true, MODE>(feat, off, ws + WS5_BASE, qf, out, b, p0,
                                      ks0, ks1, sB, sA);
    }
}

extern "C" void kernel_launch(void* const* d_in, const int* in_sizes, int n_in,
                              void* d_out, int out_size, void* d_ws, size_t ws_size,
                              hipStream_t stream)
{
    const float* feat = (const float*)d_in[0];
    const float* off  = (const float*)d_in[1];
    const float* w3   = (const float*)d_in[2];
    const float* w5   = (const float*)d_in[3];
    const float* w7   = (const float*)d_in[4];
    float* out = (float*)d_out;
    unsigned short* ws = (unsigned short*)d_ws;
    uint4* qf = (uint4*)((char*)d_ws + WBYTES);

    hipMemsetAsync(d_out, 0, (size_t)out_size * sizeof(float), stream);
    mcdc_prep_w<<<dim3(WS_TOTAL / 256), dim3(256), 0, stream>>>(w3, w5, w7, ws);

    if (ws_size >= (size_t)WBYTES + QBYTES) {
        mcdc_prep_q<<<dim3(QELEMS / 256), dim3(256), 0, stream>>>(feat, qf);
        mcdc_main<0><<<dim3(1536), dim3(512), 0, stream>>>(feat, off, ws, qf, out);
    } else {
        mcdc_main<2><<<dim3(1536), dim3(512), 0, stream>>>(feat, off, ws, nullptr, out);
    }
}

// Round 15
// 316.945 us; speedup vs baseline: 14.3721x; 14.3721x over previous
//
#include <hip/hip_runtime.h>

using bf16x8 = __attribute__((ext_vector_type(8))) short;
using f32x4  = __attribute__((ext_vector_type(4))) float;

#define HW   4096
#define CIN  256
#define OFFC 166

// ws layout: [0, WBYTES) bf16 weights fragment-major; then quad feat pack.
#define WS3_BASE 0
#define WS5_BASE 589824
#define WS7_BASE 2228224
#define WS_TOTAL 5439488                 // ushorts
#define WBYTES   (WS_TOTAL * 2)
#define QELEMS   1048576                 // 2 b * 128 c2 * 4096 pos
#define QBYTES   (QELEMS * 16)           // 16 MB quad pack

__device__ __forceinline__ unsigned short f2bf(float f) {
    unsigned u = __builtin_bit_cast(unsigned, f);
    return (unsigned short)((u + 0x7fffu + ((u >> 16) & 1u)) >> 16);   // RNE
}
__device__ __forceinline__ float bf2f(unsigned v) {
    return __builtin_bit_cast(float, v << 16);
}
__device__ __forceinline__ unsigned cvt_pk_bf16(float lo, float hi) {
    unsigned r;
    asm volatile("v_cvt_pk_bf16_f32 %0, %1, %2" : "=v"(r) : "v"(lo), "v"(hi));
    return r;
}

// ---------------- weight prep: fp32 [o][c][kh][kw] -> bf16 fragment-major ----------------
// ws[((ks*16+gm)*64+l)*8+e] = w[o=gm*16+(l&15)][c][j], r=ks*32+(l>>4)*8+e, j=r>>8, c=r&255
// (16x16x32 A-frag layout — byte-identical to the passing kernels)
__global__ __launch_bounds__(256)
void mcdc_prep_w(const float* __restrict__ w3, const float* __restrict__ w5,
                 const float* __restrict__ w7, unsigned short* __restrict__ ws)
{
    int idx = blockIdx.x * 256 + threadIdx.x;
    const float* src; int KKv, base;
    if (idx < WS5_BASE)      { src = w3; KKv = 9;  base = WS3_BASE; }
    else if (idx < WS7_BASE) { src = w5; KKv = 25; base = WS5_BASE; }
    else                     { src = w7; KKv = 49; base = WS7_BASE; }
    int rel = idx - base;
    int e  = rel & 7;
    int l  = (rel >> 3) & 63;
    int gm = (rel >> 9) & 15;
    int ks = rel >> 13;
    int o  = gm * 16 + (l & 15);
    int r  = ks * 32 + (l >> 4) * 8 + e;
    ws[idx] = f2bf(src[((size_t)o * CIN + (r & 255)) * KKv + (r >> 8)]);
}

// ---------------- feat prep: corner-quad, 2 c-planes interleaved ----------------
// q[(b*128+c2)*4096 + y*64+x] = { c0:{f(y,x),f(y,xp)},{f(yp,x),f(yp,xp)}, c1: same }
__global__ __launch_bounds__(256)
void mcdc_prep_q(const float* __restrict__ feat, uint4* __restrict__ q)
{
    int idx = blockIdx.x * 256 + threadIdx.x;          // [0, QELEMS)
    int b = idx >> 19, c2 = (idx >> 12) & 127, pos = idx & 4095;
    int y = pos >> 6, x = pos & 63;
    int xp = min(x + 1, 63), yp = min(y + 1, 63);
    const float* f0 = feat + ((size_t)(b * CIN + 2 * c2)) * HW;
    const float* f1 = f0 + HW;
    uint4 o;
    o.x = (unsigned)f2bf(f0[y  * 64 + x]) | ((unsigned)f2bf(f0[y  * 64 + xp]) << 16);
    o.y = (unsigned)f2bf(f0[yp * 64 + x]) | ((unsigned)f2bf(f0[yp * 64 + xp]) << 16);
    o.z = (unsigned)f2bf(f1[y  * 64 + x]) | ((unsigned)f2bf(f1[y  * 64 + xp]) << 16);
    o.w = (unsigned)f2bf(f1[yp * 64 + x]) | ((unsigned)f2bf(f1[yp * 64 + xp]) << 16);
    q[idx] = o;
}

// ---------------- fused sample + GEMM ----------------
// 512 threads = 8 waves. BM=256, BN=64 px, K-range [ks0,ks1).
// Wave: mh=wid&1 (m-half, mf=8), pq=wid>>1 (16-px quarter, nf=1)  [PROVEN mapping — untouched].
// Staging: thread = (pixel pxs=tid&63, c-quad coct=tid>>6); reg meta; 2-deep gather pipe.
// A-tile deduped through LDS via REG-COPY (R12-proven codegen shape). awrite = two
// full-coverage 16B-stride passes -> all 32 banks active per phase (R14's conflict fix).
// sA = linear copy of the 16KB kstep block; read offsets IDENTICAL to the proven kernel:
// (mh*8+mf)*512+lane*8 — MFMA inputs bit-identical.
// NOTE: __launch_bounds__ MUST stay (512,4) — (512,6) caps VGPR at ~84 and triggers
// catastrophic scratch spill (R13/R14: VGPR=40, 20 GB scratch traffic, 4.5 ms).
template<int K, int CH_OFF, int OC_OFF, bool ATOMIC, int MODE>
__device__ __forceinline__ void dconv(
    const float* __restrict__ feat, const float* __restrict__ off,
    const unsigned short* __restrict__ wsA, const uint4* __restrict__ qf,
    float* __restrict__ out, int b, int p0, int ks0, int ks1,
    unsigned short (&sB)[2][64][40], unsigned short (&sA)[2][8192])
{
    const int tid  = threadIdx.x;
    const int lane = tid & 63;
    const int wid  = tid >> 6;
    const int mh   = wid & 1;
    const int pq   = wid >> 1;
    const int pxs  = tid & 63;          // staging pixel
    const int coct = wid;               // staging c-quad (4 c-planes)

    const int pix = p0 + pxs, py = pix >> 6, px = pix & 63;

    // per-thread bilinear meta, double-slotted by j&1
    const uint4* qbase[2];
    const float* fbase[2];
    int   fxo[2], fyo[2];
    float mw[2][4];

    auto computeMeta = [&](int j) {
        const int s = j & 1;
        const float* ob = off + ((size_t)(b * OFFC + CH_OFF + 2 * j)) * HW + pix;
        const float oy = ob[0], ox = ob[HW];
        const float sy = (float)py + oy, sx = (float)px + ox;
        const float fy = floorf(sy), fx = floorf(sx);
        const float dy = sy - fy, dx = sx - fx;
        const int y0 = (int)fy, x0 = (int)fx;
        const bool vy0 = (y0 >= 0) & (y0 < 64), vy1 = (y0 >= -1) & (y0 < 63);
        const bool vx0 = (x0 >= 0) & (x0 < 64), vx1 = (x0 >= -1) & (x0 < 63);
        float w00 = (1.f - dy) * (1.f - dx) * ((vy0 && vx0) ? 1.f : 0.f);
        float w01 = (1.f - dy) * dx         * ((vy0 && vx1) ? 1.f : 0.f);
        float w10 = dy * (1.f - dx)         * ((vy1 && vx0) ? 1.f : 0.f);
        float w11 = dy * dx                 * ((vy1 && vx1) ? 1.f : 0.f);
        const int ya  = min(max(y0, 0), 63),     xa  = min(max(x0, 0), 63);
        const int y1c = min(max(y0 + 1, 0), 63), x1c = min(max(x0 + 1, 0), 63);
        // fold degenerate axes into weights -> stage needs no selects
        if (x1c == xa) { w00 += w01; w10 += w11; w01 = 0.f; w11 = 0.f; }
        if (y1c == ya) { w00 += w10; w01 += w11; w10 = 0.f; w11 = 0.f; }
        mw[s][0] = w00; mw[s][1] = w01; mw[s][2] = w10; mw[s][3] = w11;
        const int base = ya * 64 + xa;
        if (MODE == 0) {
            qbase[s] = qf + (((size_t)(b * 128 + coct * 2)) << 12) + base;
        } else {
            fbase[s] = feat + ((size_t)(b * CIN)) * HW + base;
            fxo[s] = x1c - xa; fyo[s] = (y1c - ya) * 64;
        }
    };

    uint4 gA0, gA1, gB0, gB1;            // MODE0 gather payload
    float fA[16], fB[16];                // MODE2 gather payload (dead under MODE0)
    uint4 aP0, aP1, aQ0, aQ1;            // A-tile payload sets (32B/thread each)

    auto gissue = [&](int ks, uint4& g0, uint4& g1, float* f) {
        const int s = (ks >> 3) & 1;
        if (MODE == 0) {
            const uint4* qp = qbase[s] + ((ks & 7) << 16);
            g0 = qp[0];
            g1 = qp[4096];
        } else {
            const float* fp = fbase[s] + ((size_t)((ks & 7) * 32 + coct * 4)) * HW;
            const int xo = fxo[s], yo = fyo[s];
#pragma unroll
            for (int e = 0; e < 4; ++e) {
                f[e*4+0] = fp[0]; f[e*4+1] = fp[xo]; f[e*4+2] = fp[yo]; f[e*4+3] = fp[yo+xo];
                fp += HW;
            }
        }
    };

    // A-tile payload: thread tid covers uint4 #tid and #(512+tid) of the 16KB kstep block
    auto gissueA = [&](int ks, uint4& h0, uint4& h1) {
        const uint4* src = (const uint4*)(wsA + (size_t)ks * 8192);
        h0 = src[tid];
        h1 = src[512 + tid];
    };
    // two full-coverage passes at 16B lane stride -> all 32 banks, conflict-free
    auto awrite = [&](int ks, const uint4& h0, const uint4& h1) {
        uint4* dst = (uint4*)(&sA[ks & 1][0]);
        dst[tid]       = h0;
        dst[512 + tid] = h1;
    };

    auto bwrite = [&](int ks, const uint4& g0, const uint4& g1, const float* f) {
        const int s = (ks >> 3) & 1;
        const float w00 = mw[s][0], w01 = mw[s][1], w10 = mw[s][2], w11 = mw[s][3];
        float v[4];
        if (MODE == 0) {
            v[0] = w00*bf2f(g0.x & 0xffff) + w01*bf2f(g0.x >> 16)
                 + w10*bf2f(g0.y & 0xffff) + w11*bf2f(g0.y >> 16);
            v[1] = w00*bf2f(g0.z & 0xffff) + w01*bf2f(g0.z >> 16)
                 + w10*bf2f(g0.w & 0xffff) + w11*bf2f(g0.w >> 16);
            v[2] = w00*bf2f(g1.x & 0xffff) + w01*bf2f(g1.x >> 16)
                 + w10*bf2f(g1.y & 0xffff) + w11*bf2f(g1.y >> 16);
            v[3] = w00*bf2f(g1.z & 0xffff) + w01*bf2f(g1.z >> 16)
                 + w10*bf2f(g1.w & 0xffff) + w11*bf2f(g1.w >> 16);
        } else {
#pragma unroll
            for (int e = 0; e < 4; ++e)
                v[e] = w00*f[e*4] + w01*f[e*4+1] + w10*f[e*4+2] + w11*f[e*4+3];
        }
        uint2 wv;
        wv.x = cvt_pk_bf16(v[0], v[1]);
        wv.y = cvt_pk_bf16(v[2], v[3]);
        *(uint2*)(&sB[ks & 1][pxs][coct * 4]) = wv;
    };

    f32x4 acc[8];
#pragma unroll
    for (int i = 0; i < 8; ++i) acc[i] = f32x4{0.f, 0.f, 0.f, 0.f};

    auto iter = [&](int ks, uint4& gc0, uint4& gc1, float* fc,
                    uint4& gn0, uint4& gn1, float* fn,
                    uint4& wc0, uint4& wc1, uint4& wn0, uint4& wn1) {
        __syncthreads();                                  // sB/sA[ks&1] staged by all
        if ((ks & 7) == 6 && ks + 2 < ks1) computeMeta((ks + 2) >> 3);
        { const int kg = min(ks + 2, ks1 - 1); gissue(kg, gn0, gn1, fn); gissueA(kg, wn0, wn1); }
        const bf16x8 bfr = *(const bf16x8*)(&sB[ks & 1][pq * 16 + (lane & 15)][(lane >> 4) * 8]);
        bf16x8 a[8];
#pragma unroll
        for (int mf = 0; mf < 8; ++mf)                    // identical offsets, via LDS
            a[mf] = *(const bf16x8*)(&sA[ks & 1][(mh * 8 + mf) * 512 + lane * 8]);
        if (ks + 1 < ks1) {
            bwrite(ks + 1, gc0, gc1, fc);                 // VALU + LDS writes fill load shadow
            awrite(ks + 1, wc0, wc1);
        }
#pragma unroll
        for (int mf = 0; mf < 8; ++mf)
            acc[mf] = __builtin_amdgcn_mfma_f32_16x16x32_bf16(a[mf], bfr, acc[mf], 0, 0, 0);
    };

    // prologue: meta, payloads for ks0 and ks0+1, stage ks0 (B and A)
    computeMeta(ks0 >> 3);
    gissue(ks0, gA0, gA1, fA);
    gissueA(ks0, aP0, aP1);
    gissue(min(ks0 + 1, ks1 - 1), gB0, gB1, fB);
    gissueA(min(ks0 + 1, ks1 - 1), aQ0, aQ1);
    bwrite(ks0, gA0, gA1, fA);
    awrite(ks0, aP0, aP1);

    for (int ks = ks0; ks < ks1; ks += 2) {               // all splits even-length
        iter(ks,     gB0, gB1, fB, gA0, gA1, fA, aQ0, aQ1, aP0, aP1);
        iter(ks + 1, gA0, gA1, fA, gB0, gB1, fB, aP0, aP1, aQ0, aQ1);
    }

    // epilogue: D layout col=lane&15, row=(lane>>4)*4+r
#pragma unroll
    for (int mf = 0; mf < 8; ++mf) {
#pragma unroll
        for (int r = 0; r < 4; ++r) {
            const int o = OC_OFF + mh * 128 + mf * 16 + (lane >> 4) * 4 + r;
            const int p = p0 + pq * 16 + (lane & 15);
            float* dst = out + ((size_t)(b * 768 + o)) * HW + p;
            if (ATOMIC) atomicAdd(dst, acc[mf][r]);
            else        *dst = acc[mf][r];
        }
    }
}

// 1536 = 8 xcd * 16 tiles * 12 roles. XCD-pinned; role 0 (k3, longest) dispatched first.
template<int MODE>
__global__ __launch_bounds__(512, 4)
void mcdc_main(const float* __restrict__ feat, const float* __restrict__ off,
               const unsigned short* __restrict__ ws, const uint4* __restrict__ qf,
               float* __restrict__ out)
{
    __shared__ __attribute__((aligned(16))) unsigned short sB[2][64][40];
    __shared__ __attribute__((aligned(16))) unsigned short sA[2][8192];

    const int bid  = blockIdx.x;
    const int xcd  = bid & 7;
    const int tl   = (bid >> 3) & 15;
    const int role = bid >> 7;              // 0..11
    const int tile = xcd * 16 + tl;         // 0..127
    const int b    = tile >> 6;
    const int p0   = (tile & 63) << 6;

    if (role == 0) {                        // k=3: 72 ksteps, whole, plain store
        dconv<3, 0, 0, false, MODE>(feat, off, ws + WS3_BASE, qf, out, b, p0, 0, 72, sB, sA);
    } else if (role <= 7) {                 // k=7: 7 splits of 56
        const int r = role - 1;
        dconv<7, 68, 512, true, MODE>(feat, off, ws + WS7_BASE, qf, out, b, p0,
                                      r * 56, r * 56 + 56, sB, sA);
    } else {                                // k=5: 200 = 48+48+48+56
        const int r = role - 8;
        const int ks0 = r * 48;
        const int ks1 = (r == 3) ? 200 : ks0 + 48;
        dconv<5, 18, 256, true, MODE>(feat, off, ws + WS5_BASE, qf, out, b, p0,
                                      ks0, ks1, sB, sA);
    }
}

extern "C" void kernel_launch(void* const* d_in, const int* in_sizes, int n_in,
                              void* d_out, int out_size, void* d_ws, size_t ws_size,
                              hipStream_t stream)
{
    const float* feat = (const float*)d_in[0];
    const float* off  = (const float*)d_in[1];
    const float* w3   = (const float*)d_in[2];
    const float* w5   = (const float*)d_in[3];
    const float* w7   = (const float*)d_in[4];
    float* out = (float*)d_out;
    unsigned short* ws = (unsigned short*)d_ws;
    uint4* qf = (uint4*)((char*)d_ws + WBYTES);

    hipMemsetAsync(d_out, 0, (size_t)out_size * sizeof(float), stream);
    mcdc_prep_w<<<dim3(WS_TOTAL / 256), dim3(256), 0, stream>>>(w3, w5, w7, ws);

    if (ws_size >= (size_t)WBYTES + QBYTES) {
        mcdc_prep_q<<<dim3(QELEMS / 256), dim3(256), 0, stream>>>(feat, qf);
        mcdc_main<0><<<dim3(1536), dim3(512), 0, stream>>>(feat, off, ws, qf, out);
    } else {
        mcdc_main<2><<<dim3(1536), dim3(512), 0, stream>>>(feat, off, ws, nullptr, out);
    }
}

// Round 18
// 315.723 us; speedup vs baseline: 14.4277x; 1.0039x over previous
//
#include <hip/hip_runtime.h>

using bf16x8 = __attribute__((ext_vector_type(8))) short;
using f32x4  = __attribute__((ext_vector_type(4))) float;

#define HW   4096
#define CIN  256
#define OFFC 166

// ws layout: [0, WBYTES) bf16 weights fragment-major; then quad feat pack.
#define WS3_BASE 0
#define WS5_BASE 589824
#define WS7_BASE 2228224
#define WS_TOTAL 5439488                 // ushorts
#define WBYTES   (WS_TOTAL * 2)
#define QELEMS   1048576                 // 2 b * 128 c2 * 4096 pos
#define QBYTES   (QELEMS * 16)           // 16 MB quad pack

__device__ __forceinline__ unsigned short f2bf(float f) {
    unsigned u = __builtin_bit_cast(unsigned, f);
    return (unsigned short)((u + 0x7fffu + ((u >> 16) & 1u)) >> 16);   // RNE
}
__device__ __forceinline__ float bf2f(unsigned v) {
    return __builtin_bit_cast(float, v << 16);
}
__device__ __forceinline__ unsigned cvt_pk_bf16(float lo, float hi) {
    unsigned r;
    asm volatile("v_cvt_pk_bf16_f32 %0, %1, %2" : "=v"(r) : "v"(lo), "v"(hi));
    return r;
}
// NOTE: v_dot2_f32_bf16 is BANNED — R17 measured absmax 2.09 (wrong-precision
// semantics on gfx950). Bilinear combine stays in f32 FMA form.

// ---------------- weight prep: fp32 [o][c][kh][kw] -> bf16 fragment-major ----------------
// ws[((ks*16+gm)*64+l)*8+e] = w[o=gm*16+(l&15)][c][j], r=ks*32+(l>>4)*8+e, j=r>>8, c=r&255
// (16x16x32 A-frag layout — byte-identical to the passing kernels)
__global__ __launch_bounds__(256)
void mcdc_prep_w(const float* __restrict__ w3, const float* __restrict__ w5,
                 const float* __restrict__ w7, unsigned short* __restrict__ ws)
{
    int idx = blockIdx.x * 256 + threadIdx.x;
    const float* src; int KKv, base;
    if (idx < WS5_BASE)      { src = w3; KKv = 9;  base = WS3_BASE; }
    else if (idx < WS7_BASE) { src = w5; KKv = 25; base = WS5_BASE; }
    else                     { src = w7; KKv = 49; base = WS7_BASE; }
    int rel = idx - base;
    int e  = rel & 7;
    int l  = (rel >> 3) & 63;
    int gm = (rel >> 9) & 15;
    int ks = rel >> 13;
    int o  = gm * 16 + (l & 15);
    int r  = ks * 32 + (l >> 4) * 8 + e;
    ws[idx] = f2bf(src[((size_t)o * CIN + (r & 255)) * KKv + (r >> 8)]);
}

// ---------------- feat prep: corner-quad, 2 c-planes interleaved ----------------
// q[(b*128+c2)*4096 + y*64+x] = { c0:{f(y,x),f(y,xp)},{f(yp,x),f(yp,xp)}, c1: same }
__global__ __launch_bounds__(256)
void mcdc_prep_q(const float* __restrict__ feat, uint4* __restrict__ q)
{
    int idx = blockIdx.x * 256 + threadIdx.x;          // [0, QELEMS)
    int b = idx >> 19, c2 = (idx >> 12) & 127, pos = idx & 4095;
    int y = pos >> 6, x = pos & 63;
    int xp = min(x + 1, 63), yp = min(y + 1, 63);
    const float* f0 = feat + ((size_t)(b * CIN + 2 * c2)) * HW;
    const float* f1 = f0 + HW;
    uint4 o;
    o.x = (unsigned)f2bf(f0[y  * 64 + x]) | ((unsigned)f2bf(f0[y  * 64 + xp]) << 16);
    o.y = (unsigned)f2bf(f0[yp * 64 + x]) | ((unsigned)f2bf(f0[yp * 64 + xp]) << 16);
    o.z = (unsigned)f2bf(f1[y  * 64 + x]) | ((unsigned)f2bf(f1[y  * 64 + xp]) << 16);
    o.w = (unsigned)f2bf(f1[yp * 64 + x]) | ((unsigned)f2bf(f1[yp * 64 + xp]) << 16);
    q[idx] = o;
}

// ---------------- fused sample + GEMM ----------------
// 512 threads = 8 waves. BM=256, BN=64 px, K-range [ks0,ks1).
// Wave: mh=wid&1 (m-half, mf=8), pq=wid>>1 (16-px quarter, nf=1)  [PROVEN mapping — untouched].
// Staging: thread = (pixel pxs=tid&63, c-quad coct=tid>>6); reg meta; 2-deep gather pipe.
// A-tile deduped through LDS via REG-COPY (R12/R15-proven shape; awrite = two full-coverage
// 16B-stride passes, conflict-free). sA = linear copy of the 16KB kstep block; A read
// offsets IDENTICAL: (mh*8+mf)*512+lane*8.
// NOTE: __launch_bounds__ MUST stay (512,4) — (512,6) caps VGPR at ~84 and triggers
// catastrophic scratch spill (R13/R14: VGPR=40, 20 GB scratch traffic, 4.5 ms).
template<int K, int CH_OFF, int OC_OFF, bool ATOMIC, int MODE>
__device__ __forceinline__ void dconv(
    const float* __restrict__ feat, const float* __restrict__ off,
    const unsigned short* __restrict__ wsA, const uint4* __restrict__ qf,
    float* __restrict__ out, int b, int p0, int ks0, int ks1,
    unsigned short (&sB)[2][64][40], unsigned short (&sA)[2][8192])
{
    const int tid  = threadIdx.x;
    const int lane = tid & 63;
    const int wid  = tid >> 6;
    const int mh   = wid & 1;
    const int pq   = wid >> 1;
    const int pxs  = tid & 63;          // staging pixel
    const int coct = wid;               // staging c-quad (4 c-planes)

    const int pix = p0 + pxs, py = pix >> 6, px = pix & 63;

    // per-thread bilinear meta, double-slotted by j&1
    const uint4* qbase[2];
    const float* fbase[2];
    int   fxo[2], fyo[2];
    float mw[2][4];

    auto computeMeta = [&](int j) {
        const int s = j & 1;
        const float* ob = off + ((size_t)(b * OFFC + CH_OFF + 2 * j)) * HW + pix;
        const float oy = ob[0], ox = ob[HW];
        const float sy = (float)py + oy, sx = (float)px + ox;
        const float fy = floorf(sy), fx = floorf(sx);
        const float dy = sy - fy, dx = sx - fx;
        const int y0 = (int)fy, x0 = (int)fx;
        const bool vy0 = (y0 >= 0) & (y0 < 64), vy1 = (y0 >= -1) & (y0 < 63);
        const bool vx0 = (x0 >= 0) & (x0 < 64), vx1 = (x0 >= -1) & (x0 < 63);
        float w00 = (1.f - dy) * (1.f - dx) * ((vy0 && vx0) ? 1.f : 0.f);
        float w01 = (1.f - dy) * dx         * ((vy0 && vx1) ? 1.f : 0.f);
        float w10 = dy * (1.f - dx)         * ((vy1 && vx0) ? 1.f : 0.f);
        float w11 = dy * dx                 * ((vy1 && vx1) ? 1.f : 0.f);
        const int ya  = min(max(y0, 0), 63),     xa  = min(max(x0, 0), 63);
        const int y1c = min(max(y0 + 1, 0), 63), x1c = min(max(x0 + 1, 0), 63);
        // fold degenerate axes into weights -> stage needs no selects
        if (x1c == xa) { w00 += w01; w10 += w11; w01 = 0.f; w11 = 0.f; }
        if (y1c == ya) { w00 += w10; w01 += w11; w10 = 0.f; w11 = 0.f; }
        mw[s][0] = w00; mw[s][1] = w01; mw[s][2] = w10; mw[s][3] = w11;
        const int base = ya * 64 + xa;
        if (MODE == 0) {
            qbase[s] = qf + (((size_t)(b * 128 + coct * 2)) << 12) + base;
        } else {
            fbase[s] = feat + ((size_t)(b * CIN)) * HW + base;
            fxo[s] = x1c - xa; fyo[s] = (y1c - ya) * 64;
        }
    };

    uint4 gA0, gA1, gB0, gB1;            // MODE0 gather payload
    float fA[16], fB[16];                // MODE2 gather payload (dead under MODE0)
    uint4 aP0, aP1, aQ0, aQ1;            // A-tile payload sets (32B/thread each)

    auto gissue = [&](int ks, uint4& g0, uint4& g1, float* f) {
        const int s = (ks >> 3) & 1;
        if (MODE == 0) {
            const uint4* qp = qbase[s] + ((ks & 7) << 16);
            g0 = qp[0];
            g1 = qp[4096];
        } else {
            const float* fp = fbase[s] + ((size_t)((ks & 7) * 32 + coct * 4)) * HW;
            const int xo = fxo[s], yo = fyo[s];
#pragma unroll
            for (int e = 0; e < 4; ++e) {
                f[e*4+0] = fp[0]; f[e*4+1] = fp[xo]; f[e*4+2] = fp[yo]; f[e*4+3] = fp[yo+xo];
                fp += HW;
            }
        }
    };

    // A-tile payload: thread tid covers uint4 #tid and #(512+tid) of the 16KB kstep block
    auto gissueA = [&](int ks, uint4& h0, uint4& h1) {
        const uint4* src = (const uint4*)(wsA + (size_t)ks * 8192);
        h0 = src[tid];
        h1 = src[512 + tid];
    };
    // two full-coverage passes at 16B lane stride -> all 32 banks, conflict-free
    auto awrite = [&](int ks, const uint4& h0, const uint4& h1) {
        uint4* dst = (uint4*)(&sA[ks & 1][0]);
        dst[tid]       = h0;
        dst[512 + tid] = h1;
    };

    auto bwrite = [&](int ks, const uint4& g0, const uint4& g1, const float* f) {
        const int s = (ks >> 3) & 1;
        const float w00 = mw[s][0], w01 = mw[s][1], w10 = mw[s][2], w11 = mw[s][3];
        float v[4];
        if (MODE == 0) {
            v[0] = w00*bf2f(g0.x & 0xffff) + w01*bf2f(g0.x >> 16)
                 + w10*bf2f(g0.y & 0xffff) + w11*bf2f(g0.y >> 16);
            v[1] = w00*bf2f(g0.z & 0xffff) + w01*bf2f(g0.z >> 16)
                 + w10*bf2f(g0.w & 0xffff) + w11*bf2f(g0.w >> 16);
            v[2] = w00*bf2f(g1.x & 0xffff) + w01*bf2f(g1.x >> 16)
                 + w10*bf2f(g1.y & 0xffff) + w11*bf2f(g1.y >> 16);
            v[3] = w00*bf2f(g1.z & 0xffff) + w01*bf2f(g1.z >> 16)
                 + w10*bf2f(g1.w & 0xffff) + w11*bf2f(g1.w >> 16);
        } else {
#pragma unroll
            for (int e = 0; e < 4; ++e)
                v[e] = w00*f[e*4] + w01*f[e*4+1] + w10*f[e*4+2] + w11*f[e*4+3];
        }
        uint2 wv;
        wv.x = cvt_pk_bf16(v[0], v[1]);
        wv.y = cvt_pk_bf16(v[2], v[3]);
        *(uint2*)(&sB[ks & 1][pxs][coct * 4]) = wv;
    };

    f32x4 acc[8];
#pragma unroll
    for (int i = 0; i < 8; ++i) acc[i] = f32x4{0.f, 0.f, 0.f, 0.f};

    auto iter = [&](int ks, uint4& gc0, uint4& gc1, float* fc,
                    uint4& gn0, uint4& gn1, float* fn,
                    uint4& wc0, uint4& wc1, uint4& wn0, uint4& wn1) {
        __syncthreads();                                  // sB/sA[ks&1] staged by all
        if ((ks & 7) == 6 && ks + 2 < ks1) computeMeta((ks + 2) >> 3);
        { const int kg = min(ks + 2, ks1 - 1); gissue(kg, gn0, gn1, fn); gissueA(kg, wn0, wn1); }
        const bf16x8 bfr = *(const bf16x8*)(&sB[ks & 1][pq * 16 + (lane & 15)][(lane >> 4) * 8]);
        bf16x8 a[8];
#pragma unroll
        for (int mf = 0; mf < 8; ++mf)                    // identical offsets, via LDS
            a[mf] = *(const bf16x8*)(&sA[ks & 1][(mh * 8 + mf) * 512 + lane * 8]);
        if (ks + 1 < ks1) {
            bwrite(ks + 1, gc0, gc1, fc);                 // VALU + LDS writes fill load shadow
            awrite(ks + 1, wc0, wc1);
        }
#pragma unroll
        for (int mf = 0; mf < 8; ++mf)
            acc[mf] = __builtin_amdgcn_mfma_f32_16x16x32_bf16(a[mf], bfr, acc[mf], 0, 0, 0);
    };

    // prologue: meta, payloads for ks0 and ks0+1, stage ks0 (B and A)
    computeMeta(ks0 >> 3);
    gissue(ks0, gA0, gA1, fA);
    gissueA(ks0, aP0, aP1);
    gissue(min(ks0 + 1, ks1 - 1), gB0, gB1, fB);
    gissueA(min(ks0 + 1, ks1 - 1), aQ0, aQ1);
    bwrite(ks0, gA0, gA1, fA);
    awrite(ks0, aP0, aP1);

    for (int ks = ks0; ks < ks1; ks += 2) {               // all splits even-length
        iter(ks,     gB0, gB1, fB, gA0, gA1, fA, aQ0, aQ1, aP0, aP1);
        iter(ks + 1, gA0, gA1, fA, gB0, gB1, fB, aP0, aP1, aQ0, aQ1);
    }

    // epilogue: D layout col=lane&15, row=(lane>>4)*4+r
#pragma unroll
    for (int mf = 0; mf < 8; ++mf) {
#pragma unroll
        for (int r = 0; r < 4; ++r) {
            const int o = OC_OFF + mh * 128 + mf * 16 + (lane >> 4) * 4 + r;
            const int p = p0 + pq * 16 + (lane & 15);
            float* dst = out + ((size_t)(b * 768 + o)) * HW + p;
            if (ATOMIC) atomicAdd(dst, acc[mf][r]);
            else        *dst = acc[mf][r];
        }
    }
}

// 1536 = 8 xcd * 16 tiles * 12 roles. XCD-pinned; role 0 (k3, longest) dispatched first.
template<int MODE>
__global__ __launch_bounds__(512, 4)
void mcdc_main(const float* __restrict__ feat, const float* __restrict__ off,
               const unsigned short* __restrict__ ws, const uint4* __restrict__ qf,
               float* __restrict__ out)
{
    __shared__ __attribute__((aligned(16))) unsigned short sB[2][64][40];
    __shared__ __attribute__((aligned(16))) unsigned short sA[2][8192];

    const int bid  = blockIdx.x;
    const int xcd  = bid & 7;
    const int tl   = (bid >> 3) & 15;
    const int role = bid >> 7;              // 0..11
    const int tile = xcd * 16 + tl;         // 0..127
    const int b    = tile >> 6;
    const int p0   = (tile & 63) << 6;

    if (role == 0) {                        // k=3: 72 ksteps, whole, plain store
        dconv<3, 0, 0, false, MODE>(feat, off, ws + WS3_BASE, qf, out, b, p0, 0, 72, sB, sA);
    } else if (role <= 7) {                 // k=7: 7 splits of 56
        const int r = role - 1;
        dconv<7, 68, 512, true, MODE>(feat, off, ws + WS7_BASE, qf, out, b, p0,
                                      r * 56, r * 56 + 56, sB, sA);
    } else {                                // k=5: 200 = 48+48+48+56
        const int r = role - 8;
        const int ks0 = r * 48;
        const int ks1 = (r == 3) ? 200 : ks0 + 48;
        dconv<5, 18, 256, true, MODE>(feat, off, ws + WS5_BASE, qf, out, b, p0,
                                      ks0, ks1, sB, sA);
    }
}

extern "C" void kernel_launch(void* const* d_in, const int* in_sizes, int n_in,
                              void* d_out, int out_size, void* d_ws, size_t ws_size,
                              hipStream_t stream)
{
    const float* feat = (const float*)d_in[0];
    const float* off  = (const float*)d_in[1];
    const float* w3   = (const float*)d_in[2];
    const float* w5   = (const float*)d_in[3];
    const float* w7   = (const float*)d_in[4];
    float* out = (float*)d_out;
    unsigned short* ws = (unsigned short*)d_ws;
    uint4* qf = (uint4*)((char*)d_ws + WBYTES);

    hipMemsetAsync(d_out, 0, (size_t)out_size * sizeof(float), stream);
    mcdc_prep_w<<<dim3(WS_TOTAL / 256), dim3(256), 0, stream>>>(w3, w5, w7, ws);

    if (ws_size >= (size_t)WBYTES + QBYTES) {
        mcdc_prep_q<<<dim3(QELEMS / 256), dim3(256), 0, stream>>>(feat, qf);
        mcdc_main<0><<<dim3(1536), dim3(512), 0, stream>>>(feat, off, ws, qf, out);
    } else {
        mcdc_main<2><<<dim3(1536), dim3(512), 0, stream>>>(feat, off, ws, nullptr, out);
    }
}